// Round 1
// 1259.353 us; speedup vs baseline: 1.1841x; 1.1841x over previous
//
#include <hip/hip_runtime.h>
#include <cstddef>

// Problem constants (B=16, S=1024, D=256, H=8 -> H2=4 heads/branch, DEPTH=32, DH=128)
static constexpr int BB = 16, SS = 1024, DD = 256;
static constexpr size_t OUTW = (size_t)BB * SS * DD;          // 4,194,304 floats: start of attn_w in d_out
#define SCALE 0.17677669529663687f                             // 1/sqrt(32)

// ---------------------------------------------------------------------------
// pack: Wcat[g] = [W_dist | W_adj] (256x256) for g in {q,k,v}; bcat likewise
// ---------------------------------------------------------------------------
__global__ __launch_bounds__(256) void pack_kernel(
    const float* __restrict__ Wqd, const float* __restrict__ Wqa,
    const float* __restrict__ Wkd, const float* __restrict__ Wka,
    const float* __restrict__ Wvd, const float* __restrict__ Wva,
    const float* __restrict__ bqd, const float* __restrict__ bqa,
    const float* __restrict__ bkd, const float* __restrict__ bka,
    const float* __restrict__ bvd, const float* __restrict__ bva,
    float* __restrict__ Wcat, float* __restrict__ bcat)
{
  int i = blockIdx.x * 256 + threadIdx.x;
  if (i < 3 * 256 * 256) {
    int g = i >> 16, r = (i >> 8) & 255, n = i & 255;
    const float* W0 = (g == 0) ? Wqd : (g == 1) ? Wkd : Wvd;
    const float* W1 = (g == 0) ? Wqa : (g == 1) ? Wka : Wva;
    Wcat[i] = (n < 128) ? W0[r * 128 + n] : W1[r * 128 + (n - 128)];
  } else {
    int j = i - 3 * 256 * 256;
    if (j < 3 * 256) {
      int g = j >> 8, n = j & 255;
      const float* b0 = (g == 0) ? bqd : (g == 1) ? bkd : bvd;
      const float* b1 = (g == 0) ? bqa : (g == 1) ? bka : bva;
      bcat[j] = (n < 128) ? b0[n] : b1[n - 128];
    }
  }
}

// ---------------------------------------------------------------------------
// gemm256 v2: Y[M x 256] = X[M x 256] @ W[256 x 256] + bias.
// 128x64 block tile, 8x4 micro-tile (32 FMA per 3 ds_read_b128), BK=16,
// double-buffered LDS + register prefetch -> 1 barrier per K-chunk, global
// latency hidden under the 512-FMA compute block. Grid (128,4) = 2 blocks/CU.
// ---------------------------------------------------------------------------
__global__ __launch_bounds__(256, 2) void gemm256_kernel(
    const float* __restrict__ X, const float* __restrict__ W,
    const float* __restrict__ bias, float* __restrict__ Y)
{
  __shared__ float As[2][16][132];   // [k][m], +4 pad
  __shared__ float Bs[2][16][68];    // [k][n], +4 pad
  const int t = threadIdx.x;
  const int m0 = blockIdx.x * 128;
  const int n0 = blockIdx.y * 64;
  const int tm = t >> 4, tn = t & 15;       // micro-tile: rows 8*tm.., cols 4*tn..
  const int rA = t >> 1, hA = (t & 1) * 8;  // A staging: row rA, k-offset hA
  const int kB = t >> 4, nqB = t & 15;      // B staging

  float acc[8][4];
#pragma unroll
  for (int i = 0; i < 8; ++i)
#pragma unroll
    for (int j = 0; j < 4; ++j) acc[i][j] = 0.f;

  const float* xrow = X + (size_t)(m0 + rA) * 256 + hA;

  // prologue: stage chunk 0 into buffer 0
  {
    float4 a0 = *(const float4*)&xrow[0];
    float4 a1 = *(const float4*)&xrow[4];
    float4 b0 = *(const float4*)&W[(size_t)kB * 256 + n0 + 4 * nqB];
    As[0][hA + 0][rA] = a0.x; As[0][hA + 1][rA] = a0.y;
    As[0][hA + 2][rA] = a0.z; As[0][hA + 3][rA] = a0.w;
    As[0][hA + 4][rA] = a1.x; As[0][hA + 5][rA] = a1.y;
    As[0][hA + 6][rA] = a1.z; As[0][hA + 7][rA] = a1.w;
    *(float4*)&Bs[0][kB][4 * nqB] = b0;
  }
  __syncthreads();

  int cur = 0;
  for (int k0 = 0; k0 < 256; k0 += 16) {
    const bool more = (k0 + 16) < 256;
    float4 na0, na1, nb0;
    if (more) {                      // prefetch next chunk (latency hides under compute)
      na0 = *(const float4*)&xrow[k0 + 16];
      na1 = *(const float4*)&xrow[k0 + 20];
      nb0 = *(const float4*)&W[(size_t)(k0 + 16 + kB) * 256 + n0 + 4 * nqB];
    }
#pragma unroll
    for (int kk = 0; kk < 16; ++kk) {
      float4 av0 = *(const float4*)&As[cur][kk][8 * tm];       // broadcast across tn
      float4 av1 = *(const float4*)&As[cur][kk][8 * tm + 4];
      float4 bv  = *(const float4*)&Bs[cur][kk][4 * tn];
      float ar[8] = {av0.x, av0.y, av0.z, av0.w, av1.x, av1.y, av1.z, av1.w};
      float br[4] = {bv.x, bv.y, bv.z, bv.w};
#pragma unroll
      for (int i = 0; i < 8; ++i)
#pragma unroll
        for (int j = 0; j < 4; ++j) acc[i][j] = fmaf(ar[i], br[j], acc[i][j]);
    }
    if (more) {
      const int nxt = cur ^ 1;       // other buffer: safe, all waves past prev barrier
      As[nxt][hA + 0][rA] = na0.x; As[nxt][hA + 1][rA] = na0.y;
      As[nxt][hA + 2][rA] = na0.z; As[nxt][hA + 3][rA] = na0.w;
      As[nxt][hA + 4][rA] = na1.x; As[nxt][hA + 5][rA] = na1.y;
      As[nxt][hA + 6][rA] = na1.z; As[nxt][hA + 7][rA] = na1.w;
      *(float4*)&Bs[nxt][kB][4 * nqB] = nb0;
      __syncthreads();
      cur = nxt;
    }
  }

  float4 bv = *(const float4*)&bias[n0 + 4 * tn];
#pragma unroll
  for (int i = 0; i < 8; ++i) {
    float4 o;
    o.x = acc[i][0] + bv.x; o.y = acc[i][1] + bv.y;
    o.z = acc[i][2] + bv.z; o.w = acc[i][3] + bv.w;
    *(float4*)&Y[(size_t)(m0 + 8 * tm + i) * 256 + n0 + 4 * tn] = o;
  }
}

// ---------------------------------------------------------------------------
// dist_stats: per (b,q) row of dist+neg -> rowmax and 1/sum(exp)
// ---------------------------------------------------------------------------
__global__ __launch_bounds__(256) void dist_stats_kernel(
    const float* __restrict__ dist, const float* __restrict__ mask,
    float* __restrict__ dmax, float* __restrict__ dinv)
{
  const int t = threadIdx.x;
  const int w = t >> 6, lane = t & 63;
  const int row = blockIdx.x * 4 + w;
  const int b = row >> 10;
  const float* dr = dist + (size_t)row * 1024;
  const float* mr = mask + b * 1024;
  float v[16];
  float m = -3.0e38f;
#pragma unroll
  for (int j = 0; j < 16; ++j) {
    int c = lane + 64 * j;
    v[j] = dr[c] - 1e9f * mr[c];
    m = fmaxf(m, v[j]);
  }
#pragma unroll
  for (int off = 32; off >= 1; off >>= 1) m = fmaxf(m, __shfl_xor(m, off));
  float s = 0.f;
#pragma unroll
  for (int j = 0; j < 16; ++j) s += __expf(v[j] - m);
#pragma unroll
  for (int off = 32; off >= 1; off >>= 1) s += __shfl_xor(s, off);
  if (lane == 0) { dmax[row] = m; dinv[row] = 1.0f / s; }
}

// ---------------------------------------------------------------------------
// attn_fused v2: block = (b, h, 16 q-rows); 4 waves, each wave owns 4 q-rows,
// each lane owns ONE column per 64-column K/V tile (c = cc*64 + lane).
//   - 16 FMAs per ds_read_b128 of K/V (was 8) -> inner-loop LDS traffic halved
//   - K/V/mask/dist/adj staged with register prefetch one tile ahead: global
//     latency hides under the 128-FMA compute instead of between barriers
//   - softmax stats: full-wave (64-lane) shuffle reductions, wave-local rows
//   - epilogue: per-wave LDS transpose-reduce in 2 passes (row pairs)
// LDS footprint unchanged (78,848 B) -> 2 blocks/CU as before.
// ---------------------------------------------------------------------------
__global__ __launch_bounds__(256, 2) void attn_fused_kernel(
    const float* __restrict__ Qc, const float* __restrict__ Kc,
    const float* __restrict__ Vc, const float* __restrict__ mask,
    const float* __restrict__ adj, const float* __restrict__ dist,
    const float* __restrict__ dmax, const float* __restrict__ dinv,
    float* __restrict__ wout, float* __restrict__ conc)
{
  __shared__ float Ls[17408];      // [16][1024] logits/e; epilogue: 4 x [64][66]
  __shared__ float KVs[64][36];    // K-tile, then V-tile staging
  const int t = threadIdx.x;
  const int bid = blockIdx.x;
  const int qb = bid & 63, h = (bid >> 6) & 7, b = bid >> 9;
  const int q0 = qb * 16;
  const int branch = h >> 2;
  const int boff = branch * 128 + (h & 3) * 32;
  const int wv = t >> 6, l = t & 63;     // wave id, lane id
  const int gr = q0 + 4 * wv;            // wave's first global q-row
  const int sr = t >> 2, sq = t & 3;     // staging: row sr (0..63), dim-quads sq, sq+4

  // ---- Q rows for this wave into registers (dead after phase 1) ----
  float Q[4][32];
  const float* qbase = Qc + ((size_t)(b * 1024 + gr)) * 256 + boff;
#pragma unroll
  for (int r = 0; r < 4; ++r)
#pragma unroll
    for (int dq = 0; dq < 8; ++dq) {
      float4 a = *(const float4*)&qbase[(size_t)r * 256 + 4 * dq];
      Q[r][4 * dq + 0] = a.x; Q[r][4 * dq + 1] = a.y;
      Q[r][4 * dq + 2] = a.z; Q[r][4 * dq + 3] = a.w;
    }

  const float* kb = Kc + (size_t)(b * 1024) * 256 + boff;
  const float* mr = mask + b * 1024;

  // -------- Phase 1: logits -> LDS (pipelined K staging) --------
  {
    float4 ka  = *(const float4*)&kb[(size_t)sr * 256 + 4 * sq];
    float4 kc2 = *(const float4*)&kb[(size_t)sr * 256 + 16 + 4 * sq];
    float ngc = -1e9f * mr[l];
    __syncthreads();
    *(float4*)&KVs[sr][4 * sq] = ka;
    *(float4*)&KVs[sr][16 + 4 * sq] = kc2;
    __syncthreads();
    for (int cc = 0; cc < 16; ++cc) {
      float4 nka, nkc2; float nng;
      if (cc < 15) {
        const int cn0 = (cc + 1) * 64;
        nka  = *(const float4*)&kb[(size_t)(cn0 + sr) * 256 + 4 * sq];
        nkc2 = *(const float4*)&kb[(size_t)(cn0 + sr) * 256 + 16 + 4 * sq];
        nng = -1e9f * mr[cn0 + l];
      }
      const int c = cc * 64 + l;
      float s0 = 0.f, s1 = 0.f, s2 = 0.f, s3 = 0.f;
#pragma unroll
      for (int dq = 0; dq < 8; ++dq) {
        float4 kv = *(const float4*)&KVs[l][4 * dq];   // conflict-free: stride 36
        s0 = fmaf(Q[0][4 * dq + 0], kv.x, s0); s0 = fmaf(Q[0][4 * dq + 1], kv.y, s0);
        s0 = fmaf(Q[0][4 * dq + 2], kv.z, s0); s0 = fmaf(Q[0][4 * dq + 3], kv.w, s0);
        s1 = fmaf(Q[1][4 * dq + 0], kv.x, s1); s1 = fmaf(Q[1][4 * dq + 1], kv.y, s1);
        s1 = fmaf(Q[1][4 * dq + 2], kv.z, s1); s1 = fmaf(Q[1][4 * dq + 3], kv.w, s1);
        s2 = fmaf(Q[2][4 * dq + 0], kv.x, s2); s2 = fmaf(Q[2][4 * dq + 1], kv.y, s2);
        s2 = fmaf(Q[2][4 * dq + 2], kv.z, s2); s2 = fmaf(Q[2][4 * dq + 3], kv.w, s2);
        s3 = fmaf(Q[3][4 * dq + 0], kv.x, s3); s3 = fmaf(Q[3][4 * dq + 1], kv.y, s3);
        s3 = fmaf(Q[3][4 * dq + 2], kv.z, s3); s3 = fmaf(Q[3][4 * dq + 3], kv.w, s3);
      }
      Ls[(4 * wv + 0) * 1024 + c] = fmaf(s0, SCALE, ngc);
      Ls[(4 * wv + 1) * 1024 + c] = fmaf(s1, SCALE, ngc);
      Ls[(4 * wv + 2) * 1024 + c] = fmaf(s2, SCALE, ngc);
      Ls[(4 * wv + 3) * 1024 + c] = fmaf(s3, SCALE, ngc);
      if (cc < 15) {
        __syncthreads();
        *(float4*)&KVs[sr][4 * sq] = nka;
        *(float4*)&KVs[sr][16 + 4 * sq] = nkc2;
        __syncthreads();
        ngc = nng;
      }
    }
  }

  // -------- Softmax stats: wave-local rows, full-wave shuffle reduce --------
  float inv[4];
#pragma unroll
  for (int r = 0; r < 4; ++r) {
    const int row = (4 * wv + r) * 1024;
    float mv = -3.0e38f;
#pragma unroll
    for (int jj = 0; jj < 16; ++jj) mv = fmaxf(mv, Ls[row + l + 64 * jj]);
#pragma unroll
    for (int off = 32; off >= 1; off >>= 1) mv = fmaxf(mv, __shfl_xor(mv, off));
    float sv = 0.f;
#pragma unroll
    for (int jj = 0; jj < 16; ++jj) {
      float e = __expf(Ls[row + l + 64 * jj] - mv);
      Ls[row + l + 64 * jj] = e;
      sv += e;
    }
#pragma unroll
    for (int off = 32; off >= 1; off >>= 1) sv += __shfl_xor(sv, off);
    inv[r] = 1.0f / sv;
  }

  // -------- Phase 2: reweight + w write + PV accumulate (pipelined) --------
  float o[4][32];
#pragma unroll
  for (int r = 0; r < 4; ++r)
#pragma unroll
    for (int d = 0; d < 32; ++d) o[r][d] = 0.f;

  const float* br_[4];
  float dmx[4], din[4];
  if (branch == 0) {
#pragma unroll
    for (int r = 0; r < 4; ++r) {
      dmx[r] = dmax[b * 1024 + gr + r];
      din[r] = dinv[b * 1024 + gr + r];
      br_[r] = dist + (size_t)(b * 1024 + gr + r) * 1024;
    }
  } else {
#pragma unroll
    for (int r = 0; r < 4; ++r) {
      dmx[r] = 0.f; din[r] = 0.f;
      br_[r] = adj + (size_t)(b * 1024 + gr + r) * 1024;
    }
  }
  const float* vb = Vc + (size_t)(b * 1024) * 256 + boff;
  const size_t wr0 = ((size_t)(b * 8 + h) * 1024 + gr) * 1024;

  float fpre[4], ngc2;
  {
    float4 va  = *(const float4*)&vb[(size_t)sr * 256 + 4 * sq];
    float4 vc2 = *(const float4*)&vb[(size_t)sr * 256 + 16 + 4 * sq];
#pragma unroll
    for (int r = 0; r < 4; ++r) fpre[r] = br_[r][l];
    ngc2 = -1e9f * mr[l];
    __syncthreads();                     // all waves done reading last K tile
    *(float4*)&KVs[sr][4 * sq] = va;
    *(float4*)&KVs[sr][16 + 4 * sq] = vc2;
    __syncthreads();
  }
  for (int cc = 0; cc < 16; ++cc) {
    const int c = cc * 64 + l;
    float4 nva, nvc2; float nf[4]; float nng;
    if (cc < 15) {
      const int cn0 = (cc + 1) * 64;
      nva  = *(const float4*)&vb[(size_t)(cn0 + sr) * 256 + 4 * sq];
      nvc2 = *(const float4*)&vb[(size_t)(cn0 + sr) * 256 + 16 + 4 * sq];
#pragma unroll
      for (int r = 0; r < 4; ++r) nf[r] = br_[r][cn0 + l];
      nng = -1e9f * mr[cn0 + l];
    }
    float w[4];
#pragma unroll
    for (int r = 0; r < 4; ++r) {
      float e = Ls[(4 * wv + r) * 1024 + c] * inv[r];
      float f;
      if (branch == 0) f = __expf(fpre[r] + ngc2 - dmx[r]) * din[r];
      else             f = fpre[r];
      w[r] = e * f;
      wout[wr0 + (size_t)r * 1024 + c] = w[r];
    }
#pragma unroll
    for (int dq = 0; dq < 8; ++dq) {
      float4 vv = *(const float4*)&KVs[l][4 * dq];
      o[0][4 * dq + 0] = fmaf(w[0], vv.x, o[0][4 * dq + 0]);
      o[0][4 * dq + 1] = fmaf(w[0], vv.y, o[0][4 * dq + 1]);
      o[0][4 * dq + 2] = fmaf(w[0], vv.z, o[0][4 * dq + 2]);
      o[0][4 * dq + 3] = fmaf(w[0], vv.w, o[0][4 * dq + 3]);
      o[1][4 * dq + 0] = fmaf(w[1], vv.x, o[1][4 * dq + 0]);
      o[1][4 * dq + 1] = fmaf(w[1], vv.y, o[1][4 * dq + 1]);
      o[1][4 * dq + 2] = fmaf(w[1], vv.z, o[1][4 * dq + 2]);
      o[1][4 * dq + 3] = fmaf(w[1], vv.w, o[1][4 * dq + 3]);
      o[2][4 * dq + 0] = fmaf(w[2], vv.x, o[2][4 * dq + 0]);
      o[2][4 * dq + 1] = fmaf(w[2], vv.y, o[2][4 * dq + 1]);
      o[2][4 * dq + 2] = fmaf(w[2], vv.z, o[2][4 * dq + 2]);
      o[2][4 * dq + 3] = fmaf(w[2], vv.w, o[2][4 * dq + 3]);
      o[3][4 * dq + 0] = fmaf(w[3], vv.x, o[3][4 * dq + 0]);
      o[3][4 * dq + 1] = fmaf(w[3], vv.y, o[3][4 * dq + 1]);
      o[3][4 * dq + 2] = fmaf(w[3], vv.z, o[3][4 * dq + 2]);
      o[3][4 * dq + 3] = fmaf(w[3], vv.w, o[3][4 * dq + 3]);
    }
    if (cc < 15) {
      __syncthreads();
      *(float4*)&KVs[sr][4 * sq] = nva;
      *(float4*)&KVs[sr][16 + 4 * sq] = nvc2;
      __syncthreads();
#pragma unroll
      for (int r = 0; r < 4; ++r) fpre[r] = nf[r];
      ngc2 = nng;
    }
  }

  // -------- Epilogue: per-wave transpose-reduce, 2 passes of 2 rows --------
  __syncthreads();                       // done reading Ls (e-values) & KVs
#pragma unroll
  for (int p = 0; p < 2; ++p) {
    const int base = wv * 4224 + l * 66; // 4224 = 64*66 per-wave region
#pragma unroll
    for (int d2 = 0; d2 < 16; ++d2) {
      float2 u; u.x = o[2 * p][2 * d2]; u.y = o[2 * p][2 * d2 + 1];
      *(float2*)&Ls[base + 2 * d2] = u;
      float2 v2; v2.x = o[2 * p + 1][2 * d2]; v2.y = o[2 * p + 1][2 * d2 + 1];
      *(float2*)&Ls[base + 32 + 2 * d2] = v2;
    }
    __syncthreads();
    {
      const int r01 = l >> 5, d = l & 31;
      float a = 0.f;
#pragma unroll
      for (int ll = 0; ll < 64; ++ll) a += Ls[wv * 4224 + ll * 66 + r01 * 32 + d];
      conc[((size_t)(b * 1024) + q0 + 4 * wv + 2 * p + r01) * 256 + boff + d] = a;
    }
    __syncthreads();
  }
}

// ---------------------------------------------------------------------------
extern "C" void kernel_launch(void* const* d_in, const int* in_sizes, int n_in,
                              void* d_out, int out_size, void* d_ws, size_t ws_size,
                              hipStream_t stream)
{
  const float* v_ori = (const float*)d_in[0];
  const float* k_ori = (const float*)d_in[1];
  const float* q_ori = (const float*)d_in[2];
  const float* mask  = (const float*)d_in[3];
  const float* adj   = (const float*)d_in[4];
  const float* dist  = (const float*)d_in[5];
  const float* Wqd = (const float*)d_in[6];  const float* bqd = (const float*)d_in[7];
  const float* Wkd = (const float*)d_in[8];  const float* bkd = (const float*)d_in[9];
  const float* Wvd = (const float*)d_in[10]; const float* bvd = (const float*)d_in[11];
  const float* Wqa = (const float*)d_in[12]; const float* bqa = (const float*)d_in[13];
  const float* Wka = (const float*)d_in[14]; const float* bka = (const float*)d_in[15];
  const float* Wva = (const float*)d_in[16]; const float* bva = (const float*)d_in[17];
  const float* Wo  = (const float*)d_in[18]; const float* bo  = (const float*)d_in[19];

  float* out = (float*)d_out;
  float* ws  = (float*)d_ws;
  float* Qc    = ws;                  // 16384*256
  float* Kc    = Qc + 4194304;
  float* Vc    = Kc + 4194304;
  float* conc  = Vc + 4194304;        // 16384*256
  float* dmaxb = conc + 4194304;      // 16384
  float* dinvb = dmaxb + 16384;       // 16384
  float* Wcat  = dinvb + 16384;       // 3*65536
  float* bcat  = Wcat + 196608;       // 3*256

  pack_kernel<<<771, 256, 0, stream>>>(Wqd, Wqa, Wkd, Wka, Wvd, Wva,
                                       bqd, bqa, bkd, bka, bvd, bva, Wcat, bcat);
  dim3 gg(128, 4);                    // 128x64 tiles over [16384 x 256]
  gemm256_kernel<<<gg, 256, 0, stream>>>(q_ori, Wcat,          bcat,       Qc);
  gemm256_kernel<<<gg, 256, 0, stream>>>(k_ori, Wcat + 65536,  bcat + 256, Kc);
  gemm256_kernel<<<gg, 256, 0, stream>>>(v_ori, Wcat + 131072, bcat + 512, Vc);
  dist_stats_kernel<<<4096, 256, 0, stream>>>(dist, mask, dmaxb, dinvb);
  attn_fused_kernel<<<8192, 256, 0, stream>>>(Qc, Kc, Vc, mask, adj, dist,
                                              dmaxb, dinvb, out + OUTW, conc);
  gemm256_kernel<<<gg, 256, 0, stream>>>(conc, Wo, bo, out);
}